// Round 8
// baseline (242.000 us; speedup 1.0000x reference)
//
#include <hip/hip_runtime.h>

// SNN membrane scan + spike + double-cumsum, fused pipeline kernel with
// counted-vmcnt software pipeline (T3/T4 pattern: raw s_barrier, never
// drain vmcnt to 0 in steady state).
//
// 256 blocks x 704 threads (11 waves), 1 block/CU. Per block: 64 channels.
// Roles: wave 0  = scan   (exact sequential membrane recurrence from LDS;
//                          publishes float(Z) per timestep into zbuf)
//        wave 1  = loader (cur -> 4-deep LDS ring via global_load_lds)
//        wave 2  = loader (vth -> 4-deep LDS ring via global_load_lds)
//        waves 3-10 = writers (ds_read_b128 + compare + 2 float4 stores;
//                              stores NEVER drained in-loop)
// Pipeline over 32 segments of 32 timesteps, ring depth 4:
//   iter s: loaders issue seg s+3 | scan consumes seg s -> zbuf[s&1]
//         | writers store seg s-1 from zbuf[(s-1)&1]
//         | loaders wait vmcnt(16) (seg s+1 confirmed; s+2,s+3 in flight)
//         | scan waits lgkmcnt(0) | all: raw s_barrier.
//
// fmaf order + integer cumsums identical to prior passing kernels -> bit-exact.
// gz test (Z==1) on float is exact: Z < 2^21.

#define T_LEN 1024
#define N_IN  512
#define BN    16384          // BATCH * N_IN
#define SEG_T 32             // timesteps per segment
#define NSEG  (T_LEN / SEG_T)   // 32
#define DEPTH 4              // LDS ring depth (prefetch distance 3)

// ---------------- global->LDS direct copy (16 B per lane, linear dest) ------
__device__ __forceinline__ void gload_lds16(const float* g, float* l) {
    __builtin_amdgcn_global_load_lds(
        (const __attribute__((address_space(1))) void*)g,
        (__attribute__((address_space(3))) void*)l, 16, 0, 0);
}

// Issue one 32-t segment of one array: 8 wave-instructions x 1 KB.
// Lane l covers t-row 4j + (l>>4), channels 4*(l&15)..+3.
// LDS layout: [t][ch] float, row stride 64 floats (256 B) -- linear dest.
__device__ __forceinline__ void issue_seg(const float* __restrict__ src,
                                          float* dst, int s, size_t goff) {
#pragma unroll
    for (int j = 0; j < SEG_T / 4; ++j) {
        gload_lds16(src + (size_t)(SEG_T * s + 4 * j) * BN + goff, dst + j * 256);
    }
}

__global__ __launch_bounds__(704, 1) void snn_fused(
        const float* __restrict__ cur, const float* __restrict__ beta,
        const float* __restrict__ vini, const float* __restrict__ vth,
        float* __restrict__ gz, float* __restrict__ zo, float* __restrict__ ml)
{
    __shared__ float ldsC[DEPTH][SEG_T * 64];   // 4 x 8 KB  cur ring
    __shared__ float ldsV[DEPTH][SEG_T * 64];   // 4 x 8 KB  vth ring
    __shared__ float zbuf[2][SEG_T][64];        // 2 x 8 KB  float(Z) (80 KB tot)

    const int lane   = threadIdx.x & 63;
    const int wave   = threadIdx.x >> 6;    // 0 scan, 1/2 loaders, 3..10 writers
    const int chbase = blockIdx.x * 64;
    const size_t goff = (size_t)chbase + (size_t)(lane >> 4) * BN
                      + (size_t)(4 * (lane & 15));

    // scan state (wave 0 only)
    float bta = 0.0f, m = 0.0f;
    int C = 0, Z = 0;
    if (wave == 0) {
        bta = beta[(chbase + lane) & (N_IN - 1)];
        m   = vini[chbase + lane];
    }

    // writer constants (waves 3..10): each lane owns one t-row x 4 channels
    const int ww      = wave - 3;           // 0..7: writer wave id
    const int row_sub = lane >> 4;          // 0..3
    const int chgrp   = lane & 15;          // 0..15 -> channels 4*chgrp..+3
    const int myrow   = 4 * ww + row_sub;   // my t-row within the segment

    // ---- prologue: issue segs 0..2; confirm seg 0; publish ----------------
    if (wave == 1) {
        issue_seg(cur, &ldsC[0][0], 0, goff);
        issue_seg(cur, &ldsC[1][0], 1, goff);
        issue_seg(cur, &ldsC[2][0], 2, goff);
    }
    if (wave == 2) {
        issue_seg(vth, &ldsV[0][0], 0, goff);
        issue_seg(vth, &ldsV[1][0], 1, goff);
        issue_seg(vth, &ldsV[2][0], 2, goff);
    }
    if (wave == 1 || wave == 2)
        asm volatile("s_waitcnt vmcnt(16)" ::: "memory");   // seg 0 complete
    __builtin_amdgcn_s_barrier();

    for (int s = 0; s <= NSEG; ++s) {
        // ---- loaders: issue seg s+3 into buffer freed at end of iter s-1 ---
        if (s + DEPTH - 1 < NSEG) {
            const int nb = (s + DEPTH - 1) & (DEPTH - 1);
            if (wave == 1) issue_seg(cur, &ldsC[nb][0], s + DEPTH - 1, goff);
            if (wave == 2) issue_seg(vth, &ldsV[nb][0], s + DEPTH - 1, goff);
        }

        // ---- scan: consume segment s, publish float(Z) per timestep --------
        if (wave == 0 && s < NSEG) {
            const int cb = s & (DEPTH - 1);
            const float* lc = &ldsC[cb][lane];
            const float* lv = &ldsV[cb][lane];
            float cc[SEG_T], vv[SEG_T];
#pragma unroll
            for (int t = 0; t < SEG_T; ++t) {   // bulk window off the chain
                cc[t] = lc[t * 64];
                vv[t] = lv[t * 64];
            }
#pragma unroll
            for (int t = 0; t < SEG_T; ++t) {
                m = fmaf(bta, m, cc[t]);              // exact same op/order
                const int sp = (m >= vv[t]) ? 1 : 0;  // Heaviside(m - vth)
                C += sp;                              // c1 cumsum (exact int)
                Z += C;                               // z double-cumsum (exact)
                zbuf[s & 1][t][lane] = (float)Z;      // off-chain publish
            }
            if (s == NSEG - 1) ml[chbase + lane] = m; // m_last (B,N)
        }

        // ---- writers: store segment s-1 -> gz/zo (no replay, no drains) ----
        if (wave >= 3 && s >= 1) {
            const int ds_ = s - 1;
            const float4 zq = *reinterpret_cast<const float4*>(
                                  &zbuf[ds_ & 1][myrow][4 * chgrp]);
            const float4 gf = make_float4(zq.x == 1.0f ? 1.0f : 0.0f,
                                          zq.y == 1.0f ? 1.0f : 0.0f,
                                          zq.z == 1.0f ? 1.0f : 0.0f,
                                          zq.w == 1.0f ? 1.0f : 0.0f);
            const size_t off = (size_t)(ds_ * 32 + myrow) * BN
                             + chbase + 4 * chgrp;
            *reinterpret_cast<float4*>(gz + off) = gf;   // Block.g forward value
            *reinterpret_cast<float4*>(zo + off) = zq;   // exact: z < 2^21
        }

        // ---- counted waits + raw barrier (no vmcnt(0) drain in steady state)
        if (s < NSEG) {
            if (wave == 1 || wave == 2) {
                // confirm seg s+1 complete; segs s+2,s+3 may stay in flight.
                if (s <= NSEG - 4)
                    asm volatile("s_waitcnt vmcnt(16)" ::: "memory");
                else if (s == NSEG - 3)
                    asm volatile("s_waitcnt vmcnt(8)" ::: "memory");
                else
                    asm volatile("s_waitcnt vmcnt(0)" ::: "memory");
            }
            if (wave == 0)
                asm volatile("s_waitcnt lgkmcnt(0)" ::: "memory");  // zbuf landed
            __builtin_amdgcn_s_barrier();
        }
    }
}

extern "C" void kernel_launch(void* const* d_in, const int* in_sizes, int n_in,
                              void* d_out, int out_size, void* d_ws, size_t ws_size,
                              hipStream_t stream) {
    const float* cur  = (const float*)d_in[0];   // (T,B,N) fp32
    const float* beta = (const float*)d_in[1];   // (N,)
    const float* vini = (const float*)d_in[2];   // (B,N)
    const float* vth  = (const float*)d_in[3];   // (T,B,N)
    float* gz = (float*)d_out;                       // (T,B,N)
    float* zo = gz + (size_t)T_LEN * BN;             // (T,B,N)
    float* ml = zo + (size_t)T_LEN * BN;             // (B,N)

    snn_fused<<<BN / 64, 704, 0, stream>>>(cur, beta, vini, vth, gz, zo, ml);
}

// Round 9
// 239.257 us; speedup vs baseline: 1.0115x; 1.0115x over previous
//
#include <hip/hip_runtime.h>

// SNN membrane scan + spike + double-cumsum, fused producer/consumer kernel.
//
// 256 blocks x 576 threads (9 waves), 1 block/CU, 64 channels/block.
//   wave 0    = scan: direct global->REGISTER double-buffered windows (no LDS
//               for inputs!). Cross-barrier prefetch forces the 2x64-float
//               window into VGPRs, so the serial fmaf chain runs register-only.
//               Publishes float(Z) per timestep into zbuf (LDS, 16 KB).
//   waves 1-8 = writers: ds_read_b128 of zbuf + compare + 2 float4 stores.
// Pipeline over 32 segments of 32 timesteps:
//   iter s: scan waits vmcnt(0) (seg s loads, issued one full period ago),
//           issues seg s+1 loads, chains seg s out of registers -> zbuf[s&1];
//           writers store seg s-1 from zbuf[(s-1)&1].  One s_barrier per iter
//           (32 barriers in both roles; stores never drained in-loop).
//
// fmaf order + integer cumsums identical to prior passing kernels -> bit-exact.
// gz test (Z==1) on float is exact: Z < 2^21.

#define T_LEN 1024
#define N_IN  512
#define BN    16384          // BATCH * N_IN
#define SEG_T 32             // timesteps per segment
#define NSEG  (T_LEN / SEG_T)   // 32

__global__ __launch_bounds__(576, 1) void snn_fused(
        const float* __restrict__ cur, const float* __restrict__ beta,
        const float* __restrict__ vini, const float* __restrict__ vth,
        float* __restrict__ gz, float* __restrict__ zo, float* __restrict__ ml)
{
    __shared__ float zbuf[2][SEG_T][64];     // 16 KB: float(Z) per t per channel

    const int lane   = threadIdx.x & 63;
    const int wave   = threadIdx.x >> 6;     // 0 = scan, 1..8 = writers
    const int chbase = blockIdx.x * 64;

    if (wave == 0) {
        // ------------------------- scan wave ---------------------------------
        const int i = chbase + lane;
        const float bta = beta[i & (N_IN - 1)];
        float m = vini[i];
        int C = 0, Z = 0;
        const float* __restrict__ cp = cur + i;
        const float* __restrict__ vp = vth + i;

        float cA[SEG_T], vA[SEG_T], cB[SEG_T], vB[SEG_T];   // 128 VGPRs

        // prologue: issue seg 0 -> window A
#pragma unroll
        for (int t = 0; t < SEG_T; ++t) {
            cA[t] = cp[(size_t)t * BN];
            vA[t] = vp[(size_t)t * BN];
        }

        // one scan step: wait own loads, prefetch segNext into Y, chain on X.
        auto step = [&](float (&Xc)[SEG_T], float (&Xv)[SEG_T],
                        float (&Yc)[SEG_T], float (&Yv)[SEG_T],
                        int segNext, float* zb) {
            asm volatile("s_waitcnt vmcnt(0)" ::: "memory");   // X complete
            if (segNext < NSEG) {
                const float* __restrict__ c2 = cp + (size_t)segNext * SEG_T * BN;
                const float* __restrict__ v2 = vp + (size_t)segNext * SEG_T * BN;
#pragma unroll
                for (int t = 0; t < SEG_T; ++t) {              // 64 loads in flight
                    Yc[t] = c2[(size_t)t * BN];
                    Yv[t] = v2[(size_t)t * BN];
                }
            }
            __builtin_amdgcn_sched_barrier(0);   // pin issue before the chain
#pragma unroll
            for (int t = 0; t < SEG_T; ++t) {
                m = fmaf(bta, m, Xc[t]);              // exact same op/order
                const int sp = (m >= Xv[t]) ? 1 : 0;  // Heaviside(m - vth)
                C += sp;                              // c1 cumsum (exact int)
                Z += C;                               // z double-cumsum (exact)
                zb[t * 64] = (float)Z;                // off-chain publish
            }
            asm volatile("s_waitcnt lgkmcnt(0)" ::: "memory"); // zbuf visible
        };

        step(cA, vA, cB, vB, 1, &zbuf[0][0][lane]);            // seg 0
        __builtin_amdgcn_s_barrier();                          // barrier #1
#pragma unroll 1
        for (int k = 0; k < (NSEG - 2) / 2; ++k) {             // k = 0..14
            step(cB, vB, cA, vA, 2 * k + 2, &zbuf[1][0][lane]);  // seg 2k+1
            __builtin_amdgcn_s_barrier();
            step(cA, vA, cB, vB, 2 * k + 3, &zbuf[0][0][lane]);  // seg 2k+2
            __builtin_amdgcn_s_barrier();
        }
        step(cB, vB, cA, vA, NSEG, &zbuf[1][0][lane]);         // seg 31, no pf
        ml[i] = m;                                             // m_last (B,N)
        __builtin_amdgcn_s_barrier();                          // barrier #32
        // writers store seg 31 after this; scan is done.
    } else {
        // ------------------------- writer waves ------------------------------
        const int ww      = wave - 1;            // 0..7
        const int row_sub = lane >> 4;           // 0..3
        const int chgrp   = lane & 15;           // 0..15 -> channels 4*chgrp..+3
        const int myrow   = 4 * ww + row_sub;    // my t-row within a segment

#pragma unroll 1
        for (int n = 0; n < NSEG; ++n) {
            __builtin_amdgcn_s_barrier();        // barrier #(n+1): seg n ready
            const float4 zq = *reinterpret_cast<const float4*>(
                                  &zbuf[n & 1][myrow][4 * chgrp]);
            const float4 gf = make_float4(zq.x == 1.0f ? 1.0f : 0.0f,
                                          zq.y == 1.0f ? 1.0f : 0.0f,
                                          zq.z == 1.0f ? 1.0f : 0.0f,
                                          zq.w == 1.0f ? 1.0f : 0.0f);
            const size_t off = (size_t)(n * 32 + myrow) * BN
                             + chbase + 4 * chgrp;
            *reinterpret_cast<float4*>(gz + off) = gf;   // Block.g forward value
            *reinterpret_cast<float4*>(zo + off) = zq;   // exact: z < 2^21
        }
        // stores never drained in-loop; kernel-end drains them.
    }
}

extern "C" void kernel_launch(void* const* d_in, const int* in_sizes, int n_in,
                              void* d_out, int out_size, void* d_ws, size_t ws_size,
                              hipStream_t stream) {
    const float* cur  = (const float*)d_in[0];   // (T,B,N) fp32
    const float* beta = (const float*)d_in[1];   // (N,)
    const float* vini = (const float*)d_in[2];   // (B,N)
    const float* vth  = (const float*)d_in[3];   // (T,B,N)
    float* gz = (float*)d_out;                       // (T,B,N)
    float* zo = gz + (size_t)T_LEN * BN;             // (T,B,N)
    float* ml = zo + (size_t)T_LEN * BN;             // (B,N)

    snn_fused<<<BN / 64, 576, 0, stream>>>(cur, beta, vini, vth, gz, zo, ml);
}